// Round 10
// baseline (340.620 us; speedup 1.0000x reference)
//
#include <hip/hip_runtime.h>
#include <math.h>

#define D_MODEL 4096
#define N_EXP   64

typedef _Float16 half8 __attribute__((ext_vector_type(8)));
typedef float    f32x4 __attribute__((ext_vector_type(4)));

// ---------------------------------------------------------------------------
// Prep: W[64][4096] fp32 -> fragment-ordered fp16 hi/lo arrays (in d_ws).
// (Verified R4-R9.)
// ---------------------------------------------------------------------------
__global__ __launch_bounds__(256)
void wprep_kernel(const float* __restrict__ W,
                  _Float16* __restrict__ whf, _Float16* __restrict__ wlf) {
    const int gid   = blockIdx.x * 256 + threadIdx.x;   // 0..32767
    const int lane  = gid & 63;
    const int ntk   = gid >> 6;
    const int nt    = ntk & 3;
    const int kstep = ntk >> 2;
    const int e  = nt * 16 + (lane & 15);
    const int k0 = kstep * 32 + (lane >> 4) * 8;

    const float* src = W + (size_t)e * D_MODEL + k0;
    float4 w0 = *(const float4*)(src);
    float4 w1 = *(const float4*)(src + 4);
    float wv[8] = {w0.x, w0.y, w0.z, w0.w, w1.x, w1.y, w1.z, w1.w};

    half8 hh, ll;
    #pragma unroll
    for (int j = 0; j < 8; ++j) {
        float ws = wv[j] * 64.0f;
        _Float16 h = (_Float16)ws;
        hh[j] = h;
        ll[j] = (_Float16)((ws - (float)h) * 4096.0f);
    }
    *(half8*)(whf + (size_t)gid * 8) = hh;
    *(half8*)(wlf + (size_t)gid * 8) = ll;
}

// global -> LDS direct (16B/lane, linear lane*16 dest = our fragment layout)
#define GLD16(gp, lp) __builtin_amdgcn_global_load_lds( \
    (const __attribute__((address_space(1))) unsigned int*)(const void*)(gp), \
    (__attribute__((address_space(3))) unsigned int*)(void*)(lp), 16, 0, 0)

__device__ __forceinline__ void cvt_hilo(const float4 a, const float4 b,
                                         half8& hi, half8& lo) {
    float av[8] = {a.x, a.y, a.z, a.w, b.x, b.y, b.z, b.w};
    #pragma unroll
    for (int j = 0; j < 8; ++j) {
        _Float16 h = (_Float16)av[j];
        hi[j] = h;
        lo[j] = (_Float16)((av[j] - (float)h) * 4096.0f);
    }
}

// ---------------------------------------------------------------------------
// DIAGNOSTIC ROUND: exact R7 structure (best: 129.5us) wrapped in a rep x3
// loop so the router (~370us) outruns the harness's ~330us ws-poison fills
// and surfaces its rocprof counters. Output written 3x identically
// (deterministic). Next round removes the rep and applies the counter-
// indicated fix.
// ---------------------------------------------------------------------------
__global__ __launch_bounds__(256, 2)
void router_kernel(const float* __restrict__ x,
                   const _Float16* __restrict__ whf,
                   const _Float16* __restrict__ wlf,
                   float* __restrict__ out, int ntok) {
    __shared__ _Float16 sB[2][4][2][4][512];   // [buf][ksl][hi/lo][nt][lane*8] = 64 KiB

    const int tid  = threadIdx.x;
    const int w    = tid >> 6;    // wave 0..3 -> token strip & staged ksl
    const int l    = tid & 63;
    const int tok0 = blockIdx.x * 64;
    const float* ax = x + (size_t)(tok0 + w * 16 + (l & 15)) * D_MODEL + (l >> 4) * 8;

    f32x4 hh[4], cc[4];
    float* out_e = out + (size_t)2 * ntok;

    for (int rep = 0; rep < 3; ++rep) {
        __syncthreads();   // prev rep's tail reads done before re-staging

        #pragma unroll
        for (int nt = 0; nt < 4; ++nt) { hh[nt] = (f32x4)0.0f; cc[nt] = (f32x4)0.0f; }

        // prologue: stage B group 0 into buf0 (wave w stages ksl=w)
        {
            const size_t co = (size_t)w * 4 * 512 + (size_t)l * 8;
            #pragma unroll
            for (int nt = 0; nt < 4; ++nt) {
                GLD16(whf + co + nt * 512, &sB[0][w][0][nt][0]);
                GLD16(wlf + co + nt * 512, &sB[0][w][1][nt][0]);
            }
        }
        // A-ring prologue: half0 = ks0-3, half1 = ks4-7
        float4 P0a = *(const float4*)(ax + 0 * 32), P0b = *(const float4*)(ax + 0 * 32 + 4);
        float4 P1a = *(const float4*)(ax + 1 * 32), P1b = *(const float4*)(ax + 1 * 32 + 4);
        float4 P2a = *(const float4*)(ax + 2 * 32), P2b = *(const float4*)(ax + 2 * 32 + 4);
        float4 P3a = *(const float4*)(ax + 3 * 32), P3b = *(const float4*)(ax + 3 * 32 + 4);
        float4 P4a = *(const float4*)(ax + 4 * 32), P4b = *(const float4*)(ax + 4 * 32 + 4);
        float4 P5a = *(const float4*)(ax + 5 * 32), P5b = *(const float4*)(ax + 5 * 32 + 4);
        float4 P6a = *(const float4*)(ax + 6 * 32), P6b = *(const float4*)(ax + 6 * 32 + 4);
        float4 P7a = *(const float4*)(ax + 7 * 32), P7b = *(const float4*)(ax + 7 * 32 + 4);

        __syncthreads();

#define STEP(KSL, SA, SB, CUR)                                                 \
    {                                                                          \
        half8 ah, al;                                                          \
        cvt_hilo(SA, SB, ah, al);                                              \
        half8 bh[4], bl[4];                                                    \
        _Pragma("unroll")                                                      \
        for (int nt = 0; nt < 4; ++nt) {                                       \
            bh[nt] = *(const half8*)&sB[CUR][KSL][0][nt][l * 8];               \
            bl[nt] = *(const half8*)&sB[CUR][KSL][1][nt][l * 8];               \
        }                                                                      \
        _Pragma("unroll")                                                      \
        for (int nt = 0; nt < 4; ++nt)                                         \
            hh[nt] = __builtin_amdgcn_mfma_f32_16x16x32_f16(ah, bh[nt], hh[nt], 0, 0, 0); \
        _Pragma("unroll")                                                      \
        for (int nt = 0; nt < 4; ++nt)                                         \
            cc[nt] = __builtin_amdgcn_mfma_f32_16x16x32_f16(ah, bl[nt], cc[nt], 0, 0, 0); \
        _Pragma("unroll")                                                      \
        for (int nt = 0; nt < 4; ++nt)                                         \
            cc[nt] = __builtin_amdgcn_mfma_f32_16x16x32_f16(al, bh[nt], cc[nt], 0, 0, 0); \
    }

#define GROUP(G, CUR, C0a,C0b,C1a,C1b,C2a,C2b,C3a,C3b,                         \
                      O0a,O0b,O1a,O1b,O2a,O2b,O3a,O3b)                         \
    {                                                                          \
        if ((G) >= 1 && (G) <= 30) {                                           \
            const size_t kb = (size_t)((G) + 1) * 4 * 32;                      \
            O0a = *(const float4*)(ax + kb + 0 * 32);                          \
            O0b = *(const float4*)(ax + kb + 0 * 32 + 4);                      \
            O1a = *(const float4*)(ax + kb + 1 * 32);                          \
            O1b = *(const float4*)(ax + kb + 1 * 32 + 4);                      \
            O2a = *(const float4*)(ax + kb + 2 * 32);                          \
            O2b = *(const float4*)(ax + kb + 2 * 32 + 4);                      \
            O3a = *(const float4*)(ax + kb + 3 * 32);                          \
            O3b = *(const float4*)(ax + kb + 3 * 32 + 4);                      \
        }                                                                      \
        if ((G) < 31) {                                                        \
            const int ksg = ((G) + 1) * 4 + w;                                 \
            const size_t co = (size_t)ksg * 4 * 512 + (size_t)l * 8;           \
            _Pragma("unroll")                                                  \
            for (int nt = 0; nt < 4; ++nt) {                                   \
                GLD16(whf + co + nt * 512, &sB[(CUR) ^ 1][w][0][nt][0]);       \
                GLD16(wlf + co + nt * 512, &sB[(CUR) ^ 1][w][1][nt][0]);       \
            }                                                                  \
        }                                                                      \
        STEP(0, C0a, C0b, CUR)                                                 \
        STEP(1, C1a, C1b, CUR)                                                 \
        STEP(2, C2a, C2b, CUR)                                                 \
        STEP(3, C3a, C3b, CUR)                                                 \
        __syncthreads();                                                       \
    }

        for (int gg = 0; gg < 16; ++gg) {
            const int g0 = gg * 2;
            GROUP(g0,     0, P0a,P0b,P1a,P1b,P2a,P2b,P3a,P3b,
                             P4a,P4b,P5a,P5b,P6a,P6b,P7a,P7b)
            GROUP(g0 + 1, 1, P4a,P4b,P5a,P5b,P6a,P6b,P7a,P7b,
                             P0a,P0b,P1a,P1b,P2a,P2b,P3a,P3b)
        }
#undef GROUP
#undef STEP

        // logits = (hh + cc*2^-12) * 2^-6; top-2 over 16-lane butterfly
        float tt[4][4];   // [nt][q]
        #pragma unroll
        for (int nt = 0; nt < 4; ++nt) {
            f32x4 tot = (hh[nt] + cc[nt] * (1.0f / 4096.0f)) * (1.0f / 64.0f);
            tt[nt][0] = tot.x; tt[nt][1] = tot.y; tt[nt][2] = tot.z; tt[nt][3] = tot.w;
        }

        #pragma unroll
        for (int q = 0; q < 4; ++q) {
            // C/D layout: col = lane&15 (expert sub), row = (lane>>4)*4 + q
            float v1 = -3.0e38f, v2 = -3.0e38f;
            int   i1 = 1 << 30,  i2 = 1 << 30;
            #pragma unroll
            for (int nt = 0; nt < 4; ++nt) {
                float v  = tt[nt][q];
                int   id = nt * 16 + (l & 15);
                if (v > v1 || (v == v1 && id < i1)) {
                    v2 = v1; i2 = i1; v1 = v; i1 = id;
                } else if (v > v2 || (v == v2 && id < i2)) {
                    v2 = v; i2 = id;
                }
            }
            #pragma unroll
            for (int m = 1; m < 16; m <<= 1) {
                float ov1 = __shfl_xor(v1, m, 64);
                int   oi1 = __shfl_xor(i1, m, 64);
                float ov2 = __shfl_xor(v2, m, 64);
                int   oi2 = __shfl_xor(i2, m, 64);
                bool ofirst = (ov1 > v1) || (ov1 == v1 && oi1 < i1);
                if (ofirst) {
                    bool s2 = (ov2 > v1) || (ov2 == v1 && oi2 < i1);
                    v2 = s2 ? ov2 : v1;  i2 = s2 ? oi2 : i1;
                    v1 = ov1;            i1 = oi1;
                } else {
                    bool s2 = (ov1 > v2) || (ov1 == v2 && oi1 < i2);
                    v2 = s2 ? ov1 : v2;  i2 = s2 ? oi1 : i2;
                }
            }

            if ((l & 15) == 0) {
                const int tok = tok0 + w * 16 + (l >> 4) * 4 + q;
                float e = expf(v2 - v1);     // <= 1
                float d = 1.0f + e;
                out[2 * tok + 0] = 1.0f / d;
                out[2 * tok + 1] = e / d;
                out_e[2 * tok + 0] = (float)i1;
                out_e[2 * tok + 1] = (float)i2;
            }
        }
    }   // rep
}

extern "C" void kernel_launch(void* const* d_in, const int* in_sizes, int n_in,
                              void* d_out, int out_size, void* d_ws, size_t ws_size,
                              hipStream_t stream) {
    const float* x = (const float*)d_in[0];
    const float* W = (const float*)d_in[1];
    float* out = (float*)d_out;
    const int ntok = in_sizes[0] / D_MODEL;   // 32768

    _Float16* whf = (_Float16*)d_ws;                           // 512 KB
    _Float16* wlf = (_Float16*)d_ws + (size_t)N_EXP * D_MODEL; // 512 KB

    wprep_kernel<<<dim3(128), dim3(256), 0, stream>>>(W, whf, wlf);
    router_kernel<<<dim3(ntok / 64), dim3(256), 0, stream>>>(x, whf, wlf, out, ntok);
}

// Round 11
// 157.470 us; speedup vs baseline: 2.1631x; 2.1631x over previous
//
#include <hip/hip_runtime.h>
#include <math.h>

#define D_MODEL 4096
#define N_EXP   64

typedef _Float16 half8 __attribute__((ext_vector_type(8)));
typedef float    f32x4 __attribute__((ext_vector_type(4)));

// ---------------------------------------------------------------------------
// Prep: W[64][4096] fp32 -> fragment-ordered fp16 hi/lo arrays (in d_ws).
// Ws = W*64; hi = fp16(Ws); lo = fp16((Ws-hi)*4096). Fragment order:
// element (kstep,nt,lane,j) at ((kstep*4+nt)*64+lane)*8+j, expert
// e = nt*16+(lane&15), k = kstep*32+(lane>>4)*8+j. (Verified R4-R10.)
// ---------------------------------------------------------------------------
__global__ __launch_bounds__(256)
void wprep_kernel(const float* __restrict__ W,
                  _Float16* __restrict__ whf, _Float16* __restrict__ wlf) {
    const int gid   = blockIdx.x * 256 + threadIdx.x;   // 0..32767
    const int lane  = gid & 63;
    const int ntk   = gid >> 6;
    const int nt    = ntk & 3;
    const int kstep = ntk >> 2;
    const int e  = nt * 16 + (lane & 15);
    const int k0 = kstep * 32 + (lane >> 4) * 8;

    const float* src = W + (size_t)e * D_MODEL + k0;
    float4 w0 = *(const float4*)(src);
    float4 w1 = *(const float4*)(src + 4);
    float wv[8] = {w0.x, w0.y, w0.z, w0.w, w1.x, w1.y, w1.z, w1.w};

    half8 hh, ll;
    #pragma unroll
    for (int j = 0; j < 8; ++j) {
        float ws = wv[j] * 64.0f;
        _Float16 h = (_Float16)ws;
        hh[j] = h;
        ll[j] = (_Float16)((ws - (float)h) * 4096.0f);
    }
    *(half8*)(whf + (size_t)gid * 8) = hh;
    *(half8*)(wlf + (size_t)gid * 8) = ll;
}

// global -> LDS direct (16B/lane, linear lane*16 dest = our fragment layout)
#define GLD16(gp, lp) __builtin_amdgcn_global_load_lds( \
    (const __attribute__((address_space(1))) unsigned int*)(const void*)(gp), \
    (__attribute__((address_space(3))) unsigned int*)(void*)(lp), 16, 0, 0)

__device__ __forceinline__ void cvt_hilo(const float4 a, const float4 b,
                                         half8& hi, half8& lo) {
    float av[8] = {a.x, a.y, a.z, a.w, b.x, b.y, b.z, b.w};
    #pragma unroll
    for (int j = 0; j < 8; ++j) {
        _Float16 h = (_Float16)av[j];
        hi[j] = h;
        lo[j] = (_Float16)((av[j] - (float)h) * 4096.0f);
    }
}

// ---------------------------------------------------------------------------
// Main: 128 thr = 2 waves x 16 tokens = 32 tokens/block, 1024 blocks
// -> 4 blocks/CU = 4 independent 2-wave barrier domains (R10 counters:
// latency-bound, all pipes <30% -> finer domains + more cover). Groups of
// 2 ksteps; sB double-buffered 32 KiB; A per-lane ring of 8 ksteps with
// refills issued 3 groups ahead of use. Barrier = __syncthreads per group;
// a domain's vmcnt drain is covered by the other 3 domains on the CU.
// ---------------------------------------------------------------------------
__global__ __launch_bounds__(128, 2)
void router_kernel(const float* __restrict__ x,
                   const _Float16* __restrict__ whf,
                   const _Float16* __restrict__ wlf,
                   float* __restrict__ out, int ntok) {
    __shared__ _Float16 sB[2][2][2][4][512];   // [buf][ksl][hi/lo][nt][lane*8] = 32 KiB

    const int tid  = threadIdx.x;
    const int w    = tid >> 6;    // wave 0..1: token strip AND hi/lo stage role
    const int l    = tid & 63;
    const int tok0 = blockIdx.x * 32;
    const float* ax = x + (size_t)(tok0 + w * 16 + (l & 15)) * D_MODEL + (l >> 4) * 8;
    const _Float16* bsrc = (w ? wlf : whf) + (size_t)l * 8;

    f32x4 hh[4], cc[4];
    #pragma unroll
    for (int nt = 0; nt < 4; ++nt) { hh[nt] = (f32x4)0.0f; cc[nt] = (f32x4)0.0f; }

    // stage B for group T into buf BUF: wave w covers hi/lo=w, ksl 0..1, nt 0..3
#define STAGE(T, BUF)                                                          \
    {                                                                          \
        _Pragma("unroll")                                                      \
        for (int ksl = 0; ksl < 2; ++ksl) {                                    \
            const int kst = 2 * (T) + ksl;                                     \
            _Pragma("unroll")                                                  \
            for (int nt = 0; nt < 4; ++nt)                                     \
                GLD16(bsrc + (size_t)(kst * 4 + nt) * 512,                     \
                      &sB[BUF][ksl][w][nt][0]);                                \
        }                                                                      \
    }

#define STEP(KSL, SA, SB_, CUR)                                                \
    {                                                                          \
        half8 ah, al;                                                          \
        cvt_hilo(SA, SB_, ah, al);                                             \
        half8 bh[4], bl[4];                                                    \
        _Pragma("unroll")                                                      \
        for (int nt = 0; nt < 4; ++nt) {                                       \
            bh[nt] = *(const half8*)&sB[CUR][KSL][0][nt][l * 8];               \
            bl[nt] = *(const half8*)&sB[CUR][KSL][1][nt][l * 8];               \
        }                                                                      \
        _Pragma("unroll")                                                      \
        for (int nt = 0; nt < 4; ++nt)                                         \
            hh[nt] = __builtin_amdgcn_mfma_f32_16x16x32_f16(ah, bh[nt], hh[nt], 0, 0, 0); \
        _Pragma("unroll")                                                      \
        for (int nt = 0; nt < 4; ++nt)                                         \
            cc[nt] = __builtin_amdgcn_mfma_f32_16x16x32_f16(ah, bl[nt], cc[nt], 0, 0, 0); \
        _Pragma("unroll")                                                      \
        for (int nt = 0; nt < 4; ++nt)                                         \
            cc[nt] = __builtin_amdgcn_mfma_f32_16x16x32_f16(al, bh[nt], cc[nt], 0, 0, 0); \
    }

    // GROUP(G): consume ksteps 2G,2G+1 from ring slots (2G)%8; refill ring
    // slots (2G+6)%8 with ksteps 2G+6,2G+7 (used in group G+3); stage B for
    // group G+1 into buf CUR^1 (read-done since barrier G-1). Barrier drains
    // this group's loads (B aged 1 group from L2 ~ready; A fresh ~350cyc ->
    // ~550cyc exposed, covered by the 3 other domains on the CU).
#define GROUP(G, CUR, C0a,C0b,C1a,C1b, R0a,R0b,R1a,R1b)                        \
    {                                                                          \
        if ((G) >= 1 && (G) <= 60) {                                           \
            const size_t kb = (size_t)(2 * (G) + 6) * 32;                      \
            R0a = *(const float4*)(ax + kb);                                   \
            R0b = *(const float4*)(ax + kb + 4);                               \
            R1a = *(const float4*)(ax + kb + 32);                              \
            R1b = *(const float4*)(ax + kb + 36);                              \
        }                                                                      \
        if ((G) <= 62) STAGE((G) + 1, (CUR) ^ 1)                               \
        STEP(0, C0a, C0b, CUR)                                                 \
        STEP(1, C1a, C1b, CUR)                                                 \
        __syncthreads();                                                       \
    }

    // prologue: A ring ksteps 0..7, B group 0 into buf 0
    STAGE(0, 0)
    float4 P0a = *(const float4*)(ax + 0 * 32), P0b = *(const float4*)(ax + 0 * 32 + 4);
    float4 P1a = *(const float4*)(ax + 1 * 32), P1b = *(const float4*)(ax + 1 * 32 + 4);
    float4 P2a = *(const float4*)(ax + 2 * 32), P2b = *(const float4*)(ax + 2 * 32 + 4);
    float4 P3a = *(const float4*)(ax + 3 * 32), P3b = *(const float4*)(ax + 3 * 32 + 4);
    float4 P4a = *(const float4*)(ax + 4 * 32), P4b = *(const float4*)(ax + 4 * 32 + 4);
    float4 P5a = *(const float4*)(ax + 5 * 32), P5b = *(const float4*)(ax + 5 * 32 + 4);
    float4 P6a = *(const float4*)(ax + 6 * 32), P6b = *(const float4*)(ax + 6 * 32 + 4);
    float4 P7a = *(const float4*)(ax + 7 * 32), P7b = *(const float4*)(ax + 7 * 32 + 4);
    __syncthreads();

    for (int gg = 0; gg < 16; ++gg) {
        const int g = gg * 4;
        GROUP(g + 0, 0, P0a,P0b,P1a,P1b, P6a,P6b,P7a,P7b)
        GROUP(g + 1, 1, P2a,P2b,P3a,P3b, P0a,P0b,P1a,P1b)
        GROUP(g + 2, 0, P4a,P4b,P5a,P5b, P2a,P2b,P3a,P3b)
        GROUP(g + 3, 1, P6a,P6b,P7a,P7b, P4a,P4b,P5a,P5b)
    }
#undef GROUP
#undef STEP
#undef STAGE

    // logits = (hh + cc*2^-12) * 2^-6; top-2 over 16-lane butterfly
    float tt[4][4];   // [nt][q]
    #pragma unroll
    for (int nt = 0; nt < 4; ++nt) {
        f32x4 tot = (hh[nt] + cc[nt] * (1.0f / 4096.0f)) * (1.0f / 64.0f);
        tt[nt][0] = tot.x; tt[nt][1] = tot.y; tt[nt][2] = tot.z; tt[nt][3] = tot.w;
    }

    float* out_e = out + (size_t)2 * ntok;

    #pragma unroll
    for (int q = 0; q < 4; ++q) {
        // C/D layout: col = lane&15 (expert sub), row = (lane>>4)*4 + q (token)
        float v1 = -3.0e38f, v2 = -3.0e38f;
        int   i1 = 1 << 30,  i2 = 1 << 30;
        #pragma unroll
        for (int nt = 0; nt < 4; ++nt) {
            float v  = tt[nt][q];
            int   id = nt * 16 + (l & 15);
            if (v > v1 || (v == v1 && id < i1)) {
                v2 = v1; i2 = i1; v1 = v; i1 = id;
            } else if (v > v2 || (v == v2 && id < i2)) {
                v2 = v; i2 = id;
            }
        }
        #pragma unroll
        for (int m = 1; m < 16; m <<= 1) {
            float ov1 = __shfl_xor(v1, m, 64);
            int   oi1 = __shfl_xor(i1, m, 64);
            float ov2 = __shfl_xor(v2, m, 64);
            int   oi2 = __shfl_xor(i2, m, 64);
            bool ofirst = (ov1 > v1) || (ov1 == v1 && oi1 < i1);
            if (ofirst) {
                bool s2 = (ov2 > v1) || (ov2 == v1 && oi2 < i1);
                v2 = s2 ? ov2 : v1;  i2 = s2 ? oi2 : i1;
                v1 = ov1;            i1 = oi1;
            } else {
                bool s2 = (ov1 > v2) || (ov1 == v2 && oi1 < i2);
                v2 = s2 ? ov1 : v2;  i2 = s2 ? oi1 : i2;
            }
        }

        if ((l & 15) == 0) {
            const int tok = tok0 + w * 16 + (l >> 4) * 4 + q;
            float e = expf(v2 - v1);     // <= 1
            float d = 1.0f + e;
            out[2 * tok + 0] = 1.0f / d;
            out[2 * tok + 1] = e / d;
            out_e[2 * tok + 0] = (float)i1;
            out_e[2 * tok + 1] = (float)i2;
        }
    }
}

extern "C" void kernel_launch(void* const* d_in, const int* in_sizes, int n_in,
                              void* d_out, int out_size, void* d_ws, size_t ws_size,
                              hipStream_t stream) {
    const float* x = (const float*)d_in[0];
    const float* W = (const float*)d_in[1];
    float* out = (float*)d_out;
    const int ntok = in_sizes[0] / D_MODEL;   // 32768

    _Float16* whf = (_Float16*)d_ws;                           // 512 KB
    _Float16* wlf = (_Float16*)d_ws + (size_t)N_EXP * D_MODEL; // 512 KB

    wprep_kernel<<<dim3(128), dim3(256), 0, stream>>>(W, whf, wlf);
    router_kernel<<<dim3(ntok / 32), dim3(128), 0, stream>>>(x, whf, wlf, out, ntok);
}